// Round 12
// baseline (252.820 us; speedup 1.0000x reference)
//
#include <hip/hip_runtime.h>
#include <hip/hip_bf16.h>
#include <cstdint>

// ---------------------------------------------------------------------------
// GemResNetBlock: two gauge-equivariant convs + Fourier ReLU + linear residual
// Round-23: round-22 (248us) raised gemm occupancy to 34% but LDS (Za 51.5K +
// Ys 10.6K + Xs 5.1K = 67.5K) capped residency at 2 blocks/CU -> B-load L2
// latency (~250cy/chunk) vs ~2.7 waves issuing ~50cy each = still ~60% stall
// (VALUBusy 54, MfmaUtil 8.7).  Fix: LDS lifetime union -- Za is dead after
// the K-loop and Ys/Xs are written only after it, so they share one buffer
// (max 51.5KB K2 / 25.9KB K1) with one extra barrier separating lifetimes:
//  -> 3 blocks/CU (6 waves/SIMD) for K2, 6 blocks/CU for K1.
// Also: staging loop uses (row = t>>5, off = (t&31)+32k) -- no div/mod by 200.
// K-loop unchanged (VGPR 52 <= 64 keeps the 8-wave regalloc class).
// Keeps: LDS-A staging, 8-wave khxnh split, reg-double-buffered B, fused
// epilogues, h-split q-half zbuild, scatter_pack CSR, packed-bf16 gathers.
#define NV     20000
#define NE     160000
#define IC1    16
#define OC     32
#define DIN    5
#define NSLOT  49
#define NOUT   160              // (o,i) = 32*5
#define YSTR   165              // LDS row stride (odd -> bank spread)
// ---------------------------------------------------------------------------
struct SlotTables {
    int n;
    int b[64], f[64], i[64], j[64];
    float v[64];
};

constexpr SlotTables make_slots() {
    SlotTables T{};
    float K[19][5][5][5] = {};   // [basis][freq][row i][col j]
    int nb = 0;
    const int BL = 2;
    auto add = [&](int f, const float (*cb)[2], const float (*sb)[2],
                   int m, int n) {
        if (f > BL) return;
        int r0 = (m == 0) ? 0 : (2 * m - 1), nr = (m == 0) ? 1 : 2;
        int c0 = (n == 0) ? 0 : (2 * n - 1), nc = (n == 0) ? 1 : 2;
        for (int a = 0; a < nr; a++)
            for (int bb = 0; bb < nc; bb++) {
                if (f == 0) {
                    K[nb][0][r0 + a][c0 + bb] = cb[a][bb];
                } else {
                    K[nb][2 * f - 1][r0 + a][c0 + bb] = cb[a][bb];
                    K[nb][2 * f    ][r0 + a][c0 + bb] = sb[a][bb];
                }
            }
        nb++;
    };
    const float ONE[2][2]  = {{1, 0}, {0, 0}};
    const float I2[2][2]   = {{1, 0}, {0, 1}};
    const float E2[2][2]   = {{0, -1}, {1, 0}};
    const float S2[2][2]   = {{1, 0}, {0, -1}};
    const float ES2[2][2]  = {{0, 1}, {1, 0}};
    const float NS2[2][2]  = {{-1, 0}, {0, 1}};
    const float C10[2][2]  = {{1, 0}, {0, 0}};
    const float C01[2][2]  = {{0, 0}, {1, 0}};
    const float CM10[2][2] = {{-1, 0}, {0, 0}};
    const float R10[2][2]  = {{1, 0}, {0, 0}};
    const float R01[2][2]  = {{0, 1}, {0, 0}};
    const float RM10[2][2] = {{-1, 0}, {0, 0}};

    for (int m = 0; m <= 2; m++)
        for (int n = 0; n <= 2; n++) {
            if (m == 0 && n == 0) {
                add(0, ONE, ONE, 0, 0);
            } else if (n == 0) {
                add(m, C10, C01, m, 0);
                add(m, C01, CM10, m, 0);
            } else if (m == 0) {
                add(n, R10, R01, 0, n);
                add(n, R01, RM10, 0, n);
            } else {
                int d = m - n;
                int f = d >= 0 ? d : -d;
                float sg = d >= 0 ? 1.f : -1.f;
                const float sgE[2][2]  = {{0, -sg}, {sg, 0}};
                const float msgI[2][2] = {{-sg, 0}, {0, -sg}};
                add(f, I2, sgE, m, n);
                add(f, E2, msgI, m, n);
                add(m + n, S2, ES2, m, n);
                add(m + n, ES2, NS2, m, n);
            }
        }
    T.n = 0;
    for (int i = 0; i < 5; i++)
        for (int b = 0; b < nb; b++)
            for (int f = 0; f < 5; f++)
                for (int j = 0; j < 5; j++)
                    if (K[b][f][i][j] != 0.0f) {
                        T.b[T.n] = b; T.f[T.n] = f; T.i[T.n] = i;
                        T.j[T.n] = j; T.v[T.n] = K[b][f][i][j];
                        T.n++;
                    }
    return T;
}

constexpr SlotTables SL = make_slots();
static_assert(SL.n == NSLOT, "expect 49 kernel-basis nonzeros");

__device__ __forceinline__ uint32_t bf16_rne(float f) {
    uint32_t u = __float_as_uint(f);
    u += 0x7fffu + ((u >> 16) & 1u);
    return u >> 16;
}

typedef __attribute__((ext_vector_type(8))) short bf16x8;   // MFMA A/B frag
typedef __attribute__((ext_vector_type(4))) float f32x4;    // MFMA C/D frag

// ---------------- M build: M[k][n], k=(c*50+j*10+q), n=(o*5+i) -------------
template<int C>
__global__ __launch_bounds__(256) void build_M(const float* __restrict__ W,
                                               float* __restrict__ M) {
    int t = blockIdx.x * 256 + threadIdx.x;
    const int K = C * 50;
    if (t >= K * NOUT) return;
    int n = t % NOUT, k = t / NOUT;
    int o = n / 5, i = n % 5;
    int c = k / 50, r50 = k % 50;
    int j = r50 / 10, q = r50 % 10;
    int f = q >> 1, r = q & 1;
    float acc = 0.f;
    #pragma unroll
    for (int s = 0; s < NSLOT; s++) {
        if (SL.j[s] == j && SL.f[s] == f && SL.i[s] == i)
            acc += SL.v[s] * W[(size_t)((SL.b[s] * 2 + r) * 32 + o) * C + c];
    }
    M[(size_t)k * NOUT + n] = acc;
}

// Swizzle M into MFMA B-fragment order (bf16):
// Mf[((ck*10+nt)*64+lane)*4+a] packs B[k0][col],B[k0+1][col]
// with k0 = ck*32 + (lane>>4)*8 + 2a, col = nt*16 + (lane&15).
template<int K>
__global__ __launch_bounds__(256) void build_Mfrag(const float* __restrict__ M,
                                                   uint32_t* __restrict__ Mf) {
    int t = blockIdx.x * 256 + threadIdx.x;
    const int total = (K / 32) * 10 * 64 * 4;
    if (t >= total) return;
    int a = t & 3;
    int idx = t >> 2;
    int lane = idx & 63; idx >>= 6;
    int nt = idx % 10;
    int ck = idx / 10;
    int col = nt * 16 + (lane & 15);
    int k0 = ck * 32 + (lane >> 4) * 8 + 2 * a;
    uint32_t lo = bf16_rne(M[(size_t)k0 * NOUT + col]);
    uint32_t hi = bf16_rne(M[(size_t)(k0 + 1) * NOUT + col]);
    Mf[t] = lo | (hi << 16);
}

// ---------------- CSR build ------------------------------------------------
__global__ __launch_bounds__(256) void hist_k(const int* __restrict__ ei,
                                              int* __restrict__ counts) {
    int e = blockIdx.x * 256 + threadIdx.x;
    if (e < NE) atomicAdd(&counts[ei[e]], 1);   // ei[e] = dst
}

__global__ __launch_bounds__(1024) void scan_k(const int* __restrict__ counts,
                                               int* __restrict__ cursor) {
    __shared__ int part[1024];
    int t = threadIdx.x;
    int base = t * 20;
    int local[20];
    int s = 0;
    #pragma unroll
    for (int k = 0; k < 20; k++) {
        int idx = base + k;
        int c = (idx < NV) ? counts[idx] : 0;
        local[k] = c; s += c;
    }
    part[t] = s;
    __syncthreads();
    for (int off = 1; off < 1024; off <<= 1) {
        int add = (t >= off) ? part[t - off] : 0;
        __syncthreads();
        part[t] += add;
        __syncthreads();
    }
    int run = (t == 0) ? 0 : part[t - 1];
    #pragma unroll
    for (int k = 0; k < 20; k++) {
        int idx = base + k;
        if (idx < NV) { cursor[idx] = run; run += local[k]; }
    }
}

// Fused scatter + edge-record pack.
__global__ __launch_bounds__(256) void scatter_pack(const int* __restrict__ ei,
                                                    const float* __restrict__ pre,
                                                    const float* __restrict__ conn,
                                                    int* __restrict__ cursor,
                                                    int* __restrict__ SRC,
                                                    float4* __restrict__ REC) {
    int e = blockIdx.x * 256 + threadIdx.x;
    if (e == 0) {
        SRC[NE] = 0;
        REC[(size_t)NE * 3 + 0] = float4{0.f, 0.f, 0.f, 0.f};
        REC[(size_t)NE * 3 + 1] = float4{0.f, 0.f, 0.f, 0.f};
        REC[(size_t)NE * 3 + 2] = float4{0.f, 0.f, 0.f, 0.f};
    }
    if (e >= NE) return;
    int pos = atomicAdd(&cursor[ei[e]], 1);
    SRC[pos] = ei[NE + e];
    float al = conn[e];
    float c1 = __cosf(al), s1 = __sinf(al);
    const float* pp = pre + (size_t)e * 10;
    REC[(size_t)pos * 3 + 0] = float4{c1, s1, pp[0], pp[1]};
    REC[(size_t)pos * 3 + 1] = float4{pp[2], pp[3], pp[4], pp[5]};
    REC[(size_t)pos * 3 + 2] = float4{pp[6], pp[7], pp[8], pp[9]};
}

// ---------------- bf16 row packing -----------------------------------------
__global__ __launch_bounds__(256) void x_pack(const float* __restrict__ x,
                                              uint4* __restrict__ xb) {
    int t = blockIdx.x * 256 + threadIdx.x;
    if (t >= NV * IC1) return;
    const float* xr = x + (size_t)t * 5;
    uint4 o;
    o.x = bf16_rne(xr[0]) | (bf16_rne(xr[1]) << 16);
    o.y = bf16_rne(xr[2]) | (bf16_rne(xr[3]) << 16);
    o.z = bf16_rne(xr[4]);
    o.w = 0;
    xb[t] = o;
}

// ---------------- Z build v6: h-split (q-halves) + packed-x + prefetch -----
template<int C>
__global__ __launch_bounds__(256) void zbuild6(const uint4* __restrict__ xb,
                                               const int*   __restrict__ SRC,
                                               const float4* __restrict__ REC,
                                               const int* __restrict__ cursor,
                                               uint32_t* __restrict__ Z,
                                               int v0, int v1) {
    __shared__ uint32_t st[3200];        // 128 pairs x 25 uints = 12.8 KB
    int tid = threadIdx.x;
    int t = blockIdx.x * 256 + tid;
    int pair = t >> 1, h = t & 1;
    int npairs = (v1 - v0) * C;
    bool valid = pair < npairs;
    int c = pair % C;
    int v = v0 + (valid ? pair / C : 0);
    int beg = 0, end = 0;
    if (valid) { beg = (v == 0) ? 0 : cursor[v - 1]; end = cursor[v]; }

    float acc[25];
    #pragma unroll
    for (int z = 0; z < 25; z++) acc[z] = 0.f;

    int k = beg;
    if (k < end) {
        int k1 = (k + 1 < end) ? k + 1 : NE;
        int k2 = (k + 2 < end) ? k + 2 : NE;
        int s0 = SRC[k], s1i = SRC[k1], s2i = SRC[k2];
        const float4* rp = REC + (size_t)k * 3;
        float4 r0 = rp[0], r1 = rp[1], r2 = rp[2];
        uint4 u0 = xb[(size_t)s0 * C + c];
        uint4 u1 = xb[(size_t)s1i * C + c];
        while (true) {
            bool more = (k1 != NE);
            int k3 = (k + 3 < end) ? k + 3 : NE;
            int s3i = SRC[k3];                          // SRC 3 ahead
            uint4 u2 = xb[(size_t)s2i * C + c];         // x 2 ahead
            const float4* rpn = REC + (size_t)k1 * 3;   // REC 1 ahead
            float4 n0 = rpn[0], n1 = rpn[1], n2 = rpn[2];
            // unpack current x (bf16<<16 is the f32 bit pattern)
            float x0 = __uint_as_float(u0.x << 16);
            float x1 = __uint_as_float(u0.x & 0xffff0000u);
            float x2 = __uint_as_float(u0.y << 16);
            float x3 = __uint_as_float(u0.y & 0xffff0000u);
            float x4 = __uint_as_float(u0.z << 16);
            // compute current edge
            float cc1 = r0.x, ss1 = r0.y;
            float cc2 = cc1 * cc1 - ss1 * ss1, ss2 = 2.f * cc1 * ss1;
            float xt[5];
            xt[0] = x0;
            xt[1] = cc1 * x1 - ss1 * x2;
            xt[2] = ss1 * x1 + cc1 * x2;
            xt[3] = cc2 * x3 - ss2 * x4;
            xt[4] = ss2 * x3 + cc2 * x4;
            // q-half select, constant component indices only
            float ph[5];
            ph[0] = h ? r1.w : r0.z;    // p5 : p0
            ph[1] = h ? r2.x : r0.w;    // p6 : p1
            ph[2] = h ? r2.y : r1.x;    // p7 : p2
            ph[3] = h ? r2.z : r1.y;    // p8 : p3
            ph[4] = h ? r2.w : r1.z;    // p9 : p4
            #pragma unroll
            for (int j = 0; j < 5; j++)
                #pragma unroll
                for (int w = 0; w < 5; w++)
                    acc[j * 5 + w] = fmaf(xt[j], ph[w], acc[j * 5 + w]);
            if (!more) break;
            k = k1; k1 = k2; k2 = k3;
            r0 = n0; r1 = n1; r2 = n2;
            u0 = u1; u1 = u2;
            s2i = s3i;
        }
    }
    // assemble the 25-uint packed row for this pair.
    uint32_t* sb = st + (tid >> 1) * 25;
    #pragma unroll
    for (int j = 0; j < 5; j++) {
        float q5v = __shfl_xor(acc[j * 5 + 0], 1);   // h=1's p5-acc -> h=0
        if (h == 0) {
            sb[j * 5 + 0] = bf16_rne(acc[j * 5 + 0]) | (bf16_rne(acc[j * 5 + 1]) << 16);
            sb[j * 5 + 1] = bf16_rne(acc[j * 5 + 2]) | (bf16_rne(acc[j * 5 + 3]) << 16);
            sb[j * 5 + 2] = bf16_rne(acc[j * 5 + 4]) | (bf16_rne(q5v) << 16);
        } else {
            sb[j * 5 + 3] = bf16_rne(acc[j * 5 + 1]) | (bf16_rne(acc[j * 5 + 2]) << 16);
            sb[j * 5 + 4] = bf16_rne(acc[j * 5 + 3]) | (bf16_rne(acc[j * 5 + 4]) << 16);
        }
    }
    __syncthreads();
    size_t gbase = (size_t)blockIdx.x * 3200;
    int pbase = blockIdx.x * 128;
    for (int i = tid; i < 3200; i += 256)
        if (pbase + i / 25 < npairs) Z[gbase + i] = st[i];
}

// ---------------- MFMA GEMM + fused epilogue, LDS-union + 8 waves ----------
// 16 rows/block, 512 threads = 8 waves (kh 4-way K-split x nh 2-way N-split).
// A-tile staged into LDS (coalesced, padded stride); Za is DEAD after the
// K-loop, so Ys (+Xs) reuse the same LDS block (one extra barrier separates
// the lifetimes) -> 51.5KB/block (K2) = 3 blocks/CU, 25.9KB (K1) = 6.
__device__ __forceinline__ void fourier_relu(float d0, float d1, float d2,
                                             float d3, float d4, float* out5) {
    float o0 = 0, o1 = 0, o2 = 0, o3 = 0, o4 = 0;
    #pragma unroll
    for (int k = 0; k < 7; k++) {
        float th = (float)k * (6.28318530717958647692f / 7.0f);
        float ck = __cosf(th), sk = __sinf(th);
        float c2k = ck * ck - sk * sk, s2k = 2.f * ck * sk;
        float sv = d0 + ck * d1 + sk * d2 + c2k * d3 + s2k * d4;
        sv = fmaxf(sv, 0.f);
        o0 += sv; o1 += sv * ck; o2 += sv * sk; o3 += sv * c2k; o4 += sv * s2k;
    }
    const float i7 = 1.0f / 7.0f;
    out5[0] = o0 * i7; out5[1] = o1 * (2.f * i7); out5[2] = o2 * (2.f * i7);
    out5[3] = o3 * (2.f * i7); out5[4] = o4 * (2.f * i7);
}

template<int K, int EPI>
__global__ __launch_bounds__(512) void gemm_fused(const uint32_t* __restrict__ Z,
                                                  const uint32_t* __restrict__ Mf,
                                                  int rows,
                                                  uint4* __restrict__ y1b,
                                                  const float* __restrict__ bias,
                                                  const float* __restrict__ xres,
                                                  const float* __restrict__ Wl,
                                                  const float* __restrict__ bl,
                                                  float* __restrict__ outp) {
    constexpr int NC = K / 32;           // K chunks
    constexpr int ZROW = K / 8;          // uint4 per Z row
    constexpr int ZPAD = K / 2 + 4;      // dwords per padded LDS row
    constexpr int ZA_DW = 16 * ZPAD;
    constexpr int YS_DW = 16 * YSTR;
    constexpr int XS_DW = (EPI == 2) ? 16 * 80 : 0;
    constexpr int SH_DW = (ZA_DW > YS_DW + XS_DW) ? ZA_DW : (YS_DW + XS_DW);
    __shared__ __align__(16) uint32_t sh[SH_DW];    // Za THEN Ys|Xs (union)
    uint32_t* Za = sh;
    float*    Ys = (float*)sh;
    float*    Xs = (float*)(sh + YS_DW);
    int t = threadIdx.x;
    int lane = t & 63;
    int wave = t >> 6;
    int nh = wave & 1, kh = wave >> 1;               // kh in 0..3
    int r0 = blockIdx.x * 16;
    int mrow = lane & 15;
    int q = lane >> 4;

    // ---- stage A tile (16 rows) into LDS, coalesced, no div/mod ----
    {
        int row = t >> 5;                // 16 rows x 32 threads
        int gr = r0 + row; if (gr >= rows) gr = rows - 1;
        const uint4* zr = (const uint4*)Z + (size_t)gr * ZROW;
        for (int off = t & 31; off < ZROW; off += 32)
            *(uint4*)&Za[row * ZPAD + off * 4] = zr[off];
    }
    __syncthreads();

    const bf16x8* mfg = (const bf16x8*)((const uint4*)Mf + lane);
    int base = (NC / 4) * kh + (kh < (NC % 4) ? kh : (NC % 4));
    int cnt  = NC / 4 + (kh < (NC % 4) ? 1 : 0);
    int cka = base, ckz = base + cnt;
    int ntb = nh * 5;

    f32x4 acc[5];
    #pragma unroll
    for (int nt = 0; nt < 5; nt++) acc[nt] = {0.f, 0.f, 0.f, 0.f};

    // prefetch B chunk cka (register double-buffer; coalesced 1KB loads)
    bf16x8 bfr[5];
    #pragma unroll
    for (int nt = 0; nt < 5; nt++)
        bfr[nt] = mfg[((size_t)cka * 10 + ntb + nt) * 64];

    for (int ck = cka; ck < ckz; ck++) {
        bf16x8 bfn[5];
        #pragma unroll
        for (int nt = 0; nt < 5; nt++) bfn[nt] = bfr[nt];
        if (ck + 1 < ckz) {
            #pragma unroll
            for (int nt = 0; nt < 5; nt++)
                bfn[nt] = mfg[((size_t)(ck + 1) * 10 + ntb + nt) * 64];
        }
        // A from LDS (padded stride; start banks uniform -> min-phase b128)
        bf16x8 af = *(const bf16x8*)&Za[mrow * ZPAD + q * 4 + ck * 16];
        #pragma unroll
        for (int nt = 0; nt < 5; nt++)
            acc[nt] = __builtin_amdgcn_mfma_f32_16x16x32_bf16(af, bfr[nt],
                                                              acc[nt], 0, 0, 0);
        #pragma unroll
        for (int nt = 0; nt < 5; nt++) bfr[nt] = bfn[nt];
    }

    __syncthreads();    // all waves done reading Za -> union region reusable

    // EPI2: stage x rows into LDS (coalesced); overlaps Ys combine below
    if (EPI == 2) {
        int gbase = blockIdx.x * 16 * 80;
        int glim = rows * 80;
        for (int i = t; i < 16 * 80; i += 512)
            Xs[i] = (gbase + i < glim) ? xres[gbase + i] : 0.f;
    }
    // Ys combine: kh0 writes, then kh1..3 add, barriers between stages.
    // C/D layout: col = lane&15, row = q*4 + reg  [verified m89/m91]
    if (kh == 0) {
        #pragma unroll
        for (int nt = 0; nt < 5; nt++) {
            int col = (ntb + nt) * 16 + mrow;
            #pragma unroll
            for (int reg = 0; reg < 4; reg++)
                Ys[(q * 4 + reg) * YSTR + col] = acc[nt][reg];
        }
    }
    __syncthreads();
    if (kh == 1) {
        #pragma unroll
        for (int nt = 0; nt < 5; nt++) {
            int col = (ntb + nt) * 16 + mrow;
            #pragma unroll
            for (int reg = 0; reg < 4; reg++)
                Ys[(q * 4 + reg) * YSTR + col] += acc[nt][reg];
        }
    }
    __syncthreads();
    if (kh == 2) {
        #pragma unroll
        for (int nt = 0; nt < 5; nt++) {
            int col = (ntb + nt) * 16 + mrow;
            #pragma unroll
            for (int reg = 0; reg < 4; reg++)
                Ys[(q * 4 + reg) * YSTR + col] += acc[nt][reg];
        }
    }
    __syncthreads();
    if (kh == 3) {
        #pragma unroll
        for (int nt = 0; nt < 5; nt++) {
            int col = (ntb + nt) * 16 + mrow;
            #pragma unroll
            for (int reg = 0; reg < 4; reg++)
                Ys[(q * 4 + reg) * YSTR + col] += acc[nt][reg];
        }
    }
    __syncthreads();
    // per-(row,ch) epilogue: 512 threads cover 16 rows x 32 ch exactly
    {
        int row = t >> 5, ch = t & 31;
        int vr = blockIdx.x * 16 + row;
        if (vr < rows) {
            const float* yr = &Ys[row * YSTR + ch * 5];
            float d0 = yr[0], d1 = yr[1], d2 = yr[2], d3 = yr[3], d4 = yr[4];
            float r5[5];
            if (EPI == 1) {
                d0 += bias[ch];
                fourier_relu(d0, d1, d2, d3, d4, r5);
                uint4 o;
                o.x = bf16_rne(r5[0]) | (bf16_rne(r5[1]) << 16);
                o.y = bf16_rne(r5[2]) | (bf16_rne(r5[3]) << 16);
                o.z = bf16_rne(r5[4]);
                o.w = 0;
                y1b[(size_t)vr * 32 + ch] = o;
            } else {
                float rr0 = 0, rr1 = 0, rr2 = 0, rr3 = 0, rr4 = 0;
                const float* xs = &Xs[row * 80];
                const float* wl = Wl + ch * IC1;
                #pragma unroll
                for (int c = 0; c < IC1; c++) {
                    float w = wl[c];
                    rr0 = fmaf(w, xs[c * 5 + 0], rr0);
                    rr1 = fmaf(w, xs[c * 5 + 1], rr1);
                    rr2 = fmaf(w, xs[c * 5 + 2], rr2);
                    rr3 = fmaf(w, xs[c * 5 + 3], rr3);
                    rr4 = fmaf(w, xs[c * 5 + 4], rr4);
                }
                float blo = bl[ch];
                d0 += bias[ch] + rr0 + blo;
                d1 += rr1 + blo;
                d2 += rr2 + blo;
                d3 += rr3 + blo;
                d4 += rr4 + blo;
                fourier_relu(d0, d1, d2, d3, d4, r5);
                float* ob = outp + ((size_t)vr * 32 + ch) * 5;
                #pragma unroll
                for (int d = 0; d < 5; d++) ob[d] = r5[d];
            }
        }
    }
}

extern "C" void kernel_launch(void* const* d_in, const int* in_sizes, int n_in,
                              void* d_out, int out_size, void* d_ws, size_t ws_size,
                              hipStream_t stream) {
    const float* x    = (const float*)d_in[0];
    const int*   ei   = (const int*)  d_in[1];
    const float* pre  = (const float*)d_in[2];
    const float* conn = (const float*)d_in[3];
    const float* W1   = (const float*)d_in[4];
    const float* b1   = (const float*)d_in[5];
    const float* W2   = (const float*)d_in[6];
    const float* b2   = (const float*)d_in[7];
    const float* Wl   = (const float*)d_in[8];
    const float* bl   = (const float*)d_in[9];
    float* out = (float*)d_out;

    const int K1 = IC1 * 50;   // 800
    const int K2 = OC  * 50;   // 1600

    // ws layout (~21MB fixed): M1 | M2 | Mf1 | Mf2 | csr | REC | SRC |
    //   Y1B (10.24MB, ALSO XB1 overlay) | Ztail
    const size_t Y_BYTES   = (size_t)NV * NOUT * sizeof(float);     // 12.8 MB
    const size_t M1_BYTES  = (size_t)K1 * NOUT * sizeof(float);     // 512 KB
    const size_t M2_BYTES  = (size_t)K2 * NOUT * sizeof(float);     // 1 MB
    const size_t MF1_BYTES = (size_t)(K1 / 32) * 10 * 64 * 16;      // 256 KB
    const size_t MF2_BYTES = (size_t)(K2 / 32) * 10 * 64 * 16;      // 512 KB
    const size_t CSR_BYTES = (size_t)(2 * NV) * sizeof(int);        // 160 KB
    const size_t REC_BYTES = (size_t)(NE + 1) * 48;                 // 7.68 MB
    const size_t SRC_BYTES = (((size_t)(NE + 1) * 4 + 15) / 16) * 16;
    const size_t Y1B_BYTES = (size_t)NV * OC * 16;                  // 10.24 MB
    char* ws = (char*)d_ws;
    float* M1 = (float*)(ws);
    float* M2 = (float*)(ws + M1_BYTES);
    uint32_t* Mf1 = (uint32_t*)(ws + M1_BYTES + M2_BYTES);
    uint32_t* Mf2 = (uint32_t*)(ws + M1_BYTES + M2_BYTES + MF1_BYTES);
    int* counts = (int*)(ws + M1_BYTES + M2_BYTES + MF1_BYTES + MF2_BYTES);
    int* cursor = counts + NV;
    size_t csr_end = M1_BYTES + M2_BYTES + MF1_BYTES + MF2_BYTES + CSR_BYTES;
    float4* REC = (float4*)(ws + csr_end);
    int*    SRC = (int*)(ws + csr_end + REC_BYTES);
    uint4*  Y1B = (uint4*)(ws + csr_end + REC_BYTES + SRC_BYTES);
    uint4*  XB1 = Y1B;                            // overlay (disjoint lifetimes)
    size_t fixed = csr_end + REC_BYTES + SRC_BYTES + Y1B_BYTES;

    // Z buffer (bf16): ws tail if it has room, else d_out
    size_t tail = (ws_size > fixed) ? (ws_size - fixed) : 0;
    uint32_t* zbuf;
    size_t zcap;
    if (tail >= Y_BYTES) { zbuf = (uint32_t*)(ws + fixed); zcap = tail; }
    else                 { zbuf = (uint32_t*)d_out;        zcap = Y_BYTES; }
    int chunk1 = (int)(zcap / ((size_t)K1 * 2)); if (chunk1 > NV) chunk1 = NV;
    int chunk2 = (int)(zcap / ((size_t)K2 * 2)); if (chunk2 > NV) chunk2 = NV;
    // balance chunks (e.g. 13125 -> 10000+10000)
    int nch1 = (NV + chunk1 - 1) / chunk1; chunk1 = (NV + nch1 - 1) / nch1;
    int nch2 = (NV + chunk2 - 1) / chunk2; chunk2 = (NV + nch2 - 1) / nch2;

    hipMemsetAsync(counts, 0, NV * sizeof(int), stream);

    build_M<IC1><<<(K1 * NOUT + 255) / 256, 256, 0, stream>>>(W1, M1);
    build_M<OC> <<<(K2 * NOUT + 255) / 256, 256, 0, stream>>>(W2, M2);
    build_Mfrag<K1><<<((K1 / 32) * 2560 + 255) / 256, 256, 0, stream>>>(M1, Mf1);
    build_Mfrag<K2><<<((K2 / 32) * 2560 + 255) / 256, 256, 0, stream>>>(M2, Mf2);

    hist_k<<<(NE + 255) / 256, 256, 0, stream>>>(ei, counts);
    scan_k<<<1, 1024, 0, stream>>>(counts, cursor);
    scatter_pack<<<(NE + 255) / 256, 256, 0, stream>>>(ei, pre, conn, cursor,
                                                       SRC, REC);
    x_pack<<<(NV * IC1 + 255) / 256, 256, 0, stream>>>(x, XB1);

    // layer 1 (fused relu+pack epilogue -> Y1B)
    for (int v0 = 0; v0 < NV; v0 += chunk1) {
        int v1 = v0 + chunk1; if (v1 > NV) v1 = NV;
        int rows = v1 - v0;
        zbuild6<IC1><<<((size_t)rows * IC1 * 2 + 255) / 256, 256, 0, stream>>>(
            XB1, SRC, REC, cursor, zbuf, v0, v1);
        gemm_fused<K1, 1><<<(rows + 15) / 16, 512, 0, stream>>>(
            zbuf, Mf1, rows, Y1B + (size_t)v0 * 32, b1,
            nullptr, nullptr, nullptr, nullptr);
    }
    // layer 2 (fused residual+relu epilogue -> out)
    for (int v0 = 0; v0 < NV; v0 += chunk2) {
        int v1 = v0 + chunk2; if (v1 > NV) v1 = NV;
        int rows = v1 - v0;
        zbuild6<OC><<<((size_t)rows * OC * 2 + 255) / 256, 256, 0, stream>>>(
            Y1B, SRC, REC, cursor, zbuf, v0, v1);
        gemm_fused<K2, 2><<<(rows + 15) / 16, 512, 0, stream>>>(
            zbuf, Mf2, rows, nullptr, b2,
            x + (size_t)v0 * (IC1 * DIN), Wl, bl, out + (size_t)v0 * NOUT);
    }
}

// Round 13
// 247.768 us; speedup vs baseline: 1.0204x; 1.0204x over previous
//
#include <hip/hip_runtime.h>
#include <hip/hip_bf16.h>
#include <cstdint>

// ---------------------------------------------------------------------------
// GemResNetBlock: two gauge-equivariant convs + Fourier ReLU + linear residual
// Round-24: round-23's VGPR=48 proves the compiler AGAIN merged the B double
// buffer (bfr/bfn copy idiom is transparent to regalloc) -> single physical
// buffer -> MFMA then load-into-same-regs -> vmcnt(0) serial ~250cy per chunk.
// Fix: explicit 2-unrolled ping-pong with two NAMED buffers pb0[5]/pb1[5]
// (load b1(ck+1); MFMA b0(ck); load b0(ck+2); MFMA b1(ck+1)) -- both live
// across MFMAs, unmergeable; wave-uniform have1/have2 guards for odd tails;
// B addressing = one pointer advanced 10240B/chunk + 5 imm-offset loads.
// Expected VGPR ~80 -> still 3 blocks/CU (6 waves/SIMD) via the LDS union.
// Keeps: LDS-A staging + union (Za dead after K-loop -> Ys/Xs reuse), 8-wave
// khxnh split, fused epilogues, h-split zbuild, scatter_pack, packed-bf16.
#define NV     20000
#define NE     160000
#define IC1    16
#define OC     32
#define DIN    5
#define NSLOT  49
#define NOUT   160              // (o,i) = 32*5
#define YSTR   165              // LDS row stride (odd -> bank spread)
// ---------------------------------------------------------------------------
struct SlotTables {
    int n;
    int b[64], f[64], i[64], j[64];
    float v[64];
};

constexpr SlotTables make_slots() {
    SlotTables T{};
    float K[19][5][5][5] = {};   // [basis][freq][row i][col j]
    int nb = 0;
    const int BL = 2;
    auto add = [&](int f, const float (*cb)[2], const float (*sb)[2],
                   int m, int n) {
        if (f > BL) return;
        int r0 = (m == 0) ? 0 : (2 * m - 1), nr = (m == 0) ? 1 : 2;
        int c0 = (n == 0) ? 0 : (2 * n - 1), nc = (n == 0) ? 1 : 2;
        for (int a = 0; a < nr; a++)
            for (int bb = 0; bb < nc; bb++) {
                if (f == 0) {
                    K[nb][0][r0 + a][c0 + bb] = cb[a][bb];
                } else {
                    K[nb][2 * f - 1][r0 + a][c0 + bb] = cb[a][bb];
                    K[nb][2 * f    ][r0 + a][c0 + bb] = sb[a][bb];
                }
            }
        nb++;
    };
    const float ONE[2][2]  = {{1, 0}, {0, 0}};
    const float I2[2][2]   = {{1, 0}, {0, 1}};
    const float E2[2][2]   = {{0, -1}, {1, 0}};
    const float S2[2][2]   = {{1, 0}, {0, -1}};
    const float ES2[2][2]  = {{0, 1}, {1, 0}};
    const float NS2[2][2]  = {{-1, 0}, {0, 1}};
    const float C10[2][2]  = {{1, 0}, {0, 0}};
    const float C01[2][2]  = {{0, 0}, {1, 0}};
    const float CM10[2][2] = {{-1, 0}, {0, 0}};
    const float R10[2][2]  = {{1, 0}, {0, 0}};
    const float R01[2][2]  = {{0, 1}, {0, 0}};
    const float RM10[2][2] = {{-1, 0}, {0, 0}};

    for (int m = 0; m <= 2; m++)
        for (int n = 0; n <= 2; n++) {
            if (m == 0 && n == 0) {
                add(0, ONE, ONE, 0, 0);
            } else if (n == 0) {
                add(m, C10, C01, m, 0);
                add(m, C01, CM10, m, 0);
            } else if (m == 0) {
                add(n, R10, R01, 0, n);
                add(n, R01, RM10, 0, n);
            } else {
                int d = m - n;
                int f = d >= 0 ? d : -d;
                float sg = d >= 0 ? 1.f : -1.f;
                const float sgE[2][2]  = {{0, -sg}, {sg, 0}};
                const float msgI[2][2] = {{-sg, 0}, {0, -sg}};
                add(f, I2, sgE, m, n);
                add(f, E2, msgI, m, n);
                add(m + n, S2, ES2, m, n);
                add(m + n, ES2, NS2, m, n);
            }
        }
    T.n = 0;
    for (int i = 0; i < 5; i++)
        for (int b = 0; b < nb; b++)
            for (int f = 0; f < 5; f++)
                for (int j = 0; j < 5; j++)
                    if (K[b][f][i][j] != 0.0f) {
                        T.b[T.n] = b; T.f[T.n] = f; T.i[T.n] = i;
                        T.j[T.n] = j; T.v[T.n] = K[b][f][i][j];
                        T.n++;
                    }
    return T;
}

constexpr SlotTables SL = make_slots();
static_assert(SL.n == NSLOT, "expect 49 kernel-basis nonzeros");

__device__ __forceinline__ uint32_t bf16_rne(float f) {
    uint32_t u = __float_as_uint(f);
    u += 0x7fffu + ((u >> 16) & 1u);
    return u >> 16;
}

typedef __attribute__((ext_vector_type(8))) short bf16x8;   // MFMA A/B frag
typedef __attribute__((ext_vector_type(4))) float f32x4;    // MFMA C/D frag

// ---------------- M build: M[k][n], k=(c*50+j*10+q), n=(o*5+i) -------------
template<int C>
__global__ __launch_bounds__(256) void build_M(const float* __restrict__ W,
                                               float* __restrict__ M) {
    int t = blockIdx.x * 256 + threadIdx.x;
    const int K = C * 50;
    if (t >= K * NOUT) return;
    int n = t % NOUT, k = t / NOUT;
    int o = n / 5, i = n % 5;
    int c = k / 50, r50 = k % 50;
    int j = r50 / 10, q = r50 % 10;
    int f = q >> 1, r = q & 1;
    float acc = 0.f;
    #pragma unroll
    for (int s = 0; s < NSLOT; s++) {
        if (SL.j[s] == j && SL.f[s] == f && SL.i[s] == i)
            acc += SL.v[s] * W[(size_t)((SL.b[s] * 2 + r) * 32 + o) * C + c];
    }
    M[(size_t)k * NOUT + n] = acc;
}

// Swizzle M into MFMA B-fragment order (bf16):
// Mf[((ck*10+nt)*64+lane)*4+a] packs B[k0][col],B[k0+1][col]
// with k0 = ck*32 + (lane>>4)*8 + 2a, col = nt*16 + (lane&15).
template<int K>
__global__ __launch_bounds__(256) void build_Mfrag(const float* __restrict__ M,
                                                   uint32_t* __restrict__ Mf) {
    int t = blockIdx.x * 256 + threadIdx.x;
    const int total = (K / 32) * 10 * 64 * 4;
    if (t >= total) return;
    int a = t & 3;
    int idx = t >> 2;
    int lane = idx & 63; idx >>= 6;
    int nt = idx % 10;
    int ck = idx / 10;
    int col = nt * 16 + (lane & 15);
    int k0 = ck * 32 + (lane >> 4) * 8 + 2 * a;
    uint32_t lo = bf16_rne(M[(size_t)k0 * NOUT + col]);
    uint32_t hi = bf16_rne(M[(size_t)(k0 + 1) * NOUT + col]);
    Mf[t] = lo | (hi << 16);
}

// ---------------- CSR build ------------------------------------------------
__global__ __launch_bounds__(256) void hist_k(const int* __restrict__ ei,
                                              int* __restrict__ counts) {
    int e = blockIdx.x * 256 + threadIdx.x;
    if (e < NE) atomicAdd(&counts[ei[e]], 1);   // ei[e] = dst
}

__global__ __launch_bounds__(1024) void scan_k(const int* __restrict__ counts,
                                               int* __restrict__ cursor) {
    __shared__ int part[1024];
    int t = threadIdx.x;
    int base = t * 20;
    int local[20];
    int s = 0;
    #pragma unroll
    for (int k = 0; k < 20; k++) {
        int idx = base + k;
        int c = (idx < NV) ? counts[idx] : 0;
        local[k] = c; s += c;
    }
    part[t] = s;
    __syncthreads();
    for (int off = 1; off < 1024; off <<= 1) {
        int add = (t >= off) ? part[t - off] : 0;
        __syncthreads();
        part[t] += add;
        __syncthreads();
    }
    int run = (t == 0) ? 0 : part[t - 1];
    #pragma unroll
    for (int k = 0; k < 20; k++) {
        int idx = base + k;
        if (idx < NV) { cursor[idx] = run; run += local[k]; }
    }
}

// Fused scatter + edge-record pack.
__global__ __launch_bounds__(256) void scatter_pack(const int* __restrict__ ei,
                                                    const float* __restrict__ pre,
                                                    const float* __restrict__ conn,
                                                    int* __restrict__ cursor,
                                                    int* __restrict__ SRC,
                                                    float4* __restrict__ REC) {
    int e = blockIdx.x * 256 + threadIdx.x;
    if (e == 0) {
        SRC[NE] = 0;
        REC[(size_t)NE * 3 + 0] = float4{0.f, 0.f, 0.f, 0.f};
        REC[(size_t)NE * 3 + 1] = float4{0.f, 0.f, 0.f, 0.f};
        REC[(size_t)NE * 3 + 2] = float4{0.f, 0.f, 0.f, 0.f};
    }
    if (e >= NE) return;
    int pos = atomicAdd(&cursor[ei[e]], 1);
    SRC[pos] = ei[NE + e];
    float al = conn[e];
    float c1 = __cosf(al), s1 = __sinf(al);
    const float* pp = pre + (size_t)e * 10;
    REC[(size_t)pos * 3 + 0] = float4{c1, s1, pp[0], pp[1]};
    REC[(size_t)pos * 3 + 1] = float4{pp[2], pp[3], pp[4], pp[5]};
    REC[(size_t)pos * 3 + 2] = float4{pp[6], pp[7], pp[8], pp[9]};
}

// ---------------- bf16 row packing -----------------------------------------
__global__ __launch_bounds__(256) void x_pack(const float* __restrict__ x,
                                              uint4* __restrict__ xb) {
    int t = blockIdx.x * 256 + threadIdx.x;
    if (t >= NV * IC1) return;
    const float* xr = x + (size_t)t * 5;
    uint4 o;
    o.x = bf16_rne(xr[0]) | (bf16_rne(xr[1]) << 16);
    o.y = bf16_rne(xr[2]) | (bf16_rne(xr[3]) << 16);
    o.z = bf16_rne(xr[4]);
    o.w = 0;
    xb[t] = o;
}

// ---------------- Z build v6: h-split (q-halves) + packed-x + prefetch -----
template<int C>
__global__ __launch_bounds__(256) void zbuild6(const uint4* __restrict__ xb,
                                               const int*   __restrict__ SRC,
                                               const float4* __restrict__ REC,
                                               const int* __restrict__ cursor,
                                               uint32_t* __restrict__ Z,
                                               int v0, int v1) {
    __shared__ uint32_t st[3200];        // 128 pairs x 25 uints = 12.8 KB
    int tid = threadIdx.x;
    int t = blockIdx.x * 256 + tid;
    int pair = t >> 1, h = t & 1;
    int npairs = (v1 - v0) * C;
    bool valid = pair < npairs;
    int c = pair % C;
    int v = v0 + (valid ? pair / C : 0);
    int beg = 0, end = 0;
    if (valid) { beg = (v == 0) ? 0 : cursor[v - 1]; end = cursor[v]; }

    float acc[25];
    #pragma unroll
    for (int z = 0; z < 25; z++) acc[z] = 0.f;

    int k = beg;
    if (k < end) {
        int k1 = (k + 1 < end) ? k + 1 : NE;
        int k2 = (k + 2 < end) ? k + 2 : NE;
        int s0 = SRC[k], s1i = SRC[k1], s2i = SRC[k2];
        const float4* rp = REC + (size_t)k * 3;
        float4 r0 = rp[0], r1 = rp[1], r2 = rp[2];
        uint4 u0 = xb[(size_t)s0 * C + c];
        uint4 u1 = xb[(size_t)s1i * C + c];
        while (true) {
            bool more = (k1 != NE);
            int k3 = (k + 3 < end) ? k + 3 : NE;
            int s3i = SRC[k3];                          // SRC 3 ahead
            uint4 u2 = xb[(size_t)s2i * C + c];         // x 2 ahead
            const float4* rpn = REC + (size_t)k1 * 3;   // REC 1 ahead
            float4 n0 = rpn[0], n1 = rpn[1], n2 = rpn[2];
            // unpack current x (bf16<<16 is the f32 bit pattern)
            float x0 = __uint_as_float(u0.x << 16);
            float x1 = __uint_as_float(u0.x & 0xffff0000u);
            float x2 = __uint_as_float(u0.y << 16);
            float x3 = __uint_as_float(u0.y & 0xffff0000u);
            float x4 = __uint_as_float(u0.z << 16);
            // compute current edge
            float cc1 = r0.x, ss1 = r0.y;
            float cc2 = cc1 * cc1 - ss1 * ss1, ss2 = 2.f * cc1 * ss1;
            float xt[5];
            xt[0] = x0;
            xt[1] = cc1 * x1 - ss1 * x2;
            xt[2] = ss1 * x1 + cc1 * x2;
            xt[3] = cc2 * x3 - ss2 * x4;
            xt[4] = ss2 * x3 + cc2 * x4;
            // q-half select, constant component indices only
            float ph[5];
            ph[0] = h ? r1.w : r0.z;    // p5 : p0
            ph[1] = h ? r2.x : r0.w;    // p6 : p1
            ph[2] = h ? r2.y : r1.x;    // p7 : p2
            ph[3] = h ? r2.z : r1.y;    // p8 : p3
            ph[4] = h ? r2.w : r1.z;    // p9 : p4
            #pragma unroll
            for (int j = 0; j < 5; j++)
                #pragma unroll
                for (int w = 0; w < 5; w++)
                    acc[j * 5 + w] = fmaf(xt[j], ph[w], acc[j * 5 + w]);
            if (!more) break;
            k = k1; k1 = k2; k2 = k3;
            r0 = n0; r1 = n1; r2 = n2;
            u0 = u1; u1 = u2;
            s2i = s3i;
        }
    }
    // assemble the 25-uint packed row for this pair.
    uint32_t* sb = st + (tid >> 1) * 25;
    #pragma unroll
    for (int j = 0; j < 5; j++) {
        float q5v = __shfl_xor(acc[j * 5 + 0], 1);   // h=1's p5-acc -> h=0
        if (h == 0) {
            sb[j * 5 + 0] = bf16_rne(acc[j * 5 + 0]) | (bf16_rne(acc[j * 5 + 1]) << 16);
            sb[j * 5 + 1] = bf16_rne(acc[j * 5 + 2]) | (bf16_rne(acc[j * 5 + 3]) << 16);
            sb[j * 5 + 2] = bf16_rne(acc[j * 5 + 4]) | (bf16_rne(q5v) << 16);
        } else {
            sb[j * 5 + 3] = bf16_rne(acc[j * 5 + 1]) | (bf16_rne(acc[j * 5 + 2]) << 16);
            sb[j * 5 + 4] = bf16_rne(acc[j * 5 + 3]) | (bf16_rne(acc[j * 5 + 4]) << 16);
        }
    }
    __syncthreads();
    size_t gbase = (size_t)blockIdx.x * 3200;
    int pbase = blockIdx.x * 128;
    for (int i = tid; i < 3200; i += 256)
        if (pbase + i / 25 < npairs) Z[gbase + i] = st[i];
}

// ---------------- MFMA GEMM + fused epilogue, ping-pong B ------------------
// 16 rows/block, 512 threads = 8 waves (kh 4-way K-split x nh 2-way N-split).
// A staged in LDS (union'd with Ys/Xs); B via explicit 2-unrolled ping-pong
// (pb0[5]/pb1[5] both live across MFMAs -> compiler cannot merge them), one
// pointer += 640 bf16x8 per chunk, 5 imm-offset loads.
__device__ __forceinline__ void fourier_relu(float d0, float d1, float d2,
                                             float d3, float d4, float* out5) {
    float o0 = 0, o1 = 0, o2 = 0, o3 = 0, o4 = 0;
    #pragma unroll
    for (int k = 0; k < 7; k++) {
        float th = (float)k * (6.28318530717958647692f / 7.0f);
        float ck = __cosf(th), sk = __sinf(th);
        float c2k = ck * ck - sk * sk, s2k = 2.f * ck * sk;
        float sv = d0 + ck * d1 + sk * d2 + c2k * d3 + s2k * d4;
        sv = fmaxf(sv, 0.f);
        o0 += sv; o1 += sv * ck; o2 += sv * sk; o3 += sv * c2k; o4 += sv * s2k;
    }
    const float i7 = 1.0f / 7.0f;
    out5[0] = o0 * i7; out5[1] = o1 * (2.f * i7); out5[2] = o2 * (2.f * i7);
    out5[3] = o3 * (2.f * i7); out5[4] = o4 * (2.f * i7);
}

template<int K, int EPI>
__global__ __launch_bounds__(512) void gemm_fused(const uint32_t* __restrict__ Z,
                                                  const uint32_t* __restrict__ Mf,
                                                  int rows,
                                                  uint4* __restrict__ y1b,
                                                  const float* __restrict__ bias,
                                                  const float* __restrict__ xres,
                                                  const float* __restrict__ Wl,
                                                  const float* __restrict__ bl,
                                                  float* __restrict__ outp) {
    constexpr int NC = K / 32;           // K chunks
    constexpr int ZROW = K / 8;          // uint4 per Z row
    constexpr int ZPAD = K / 2 + 4;      // dwords per padded LDS row
    constexpr int ZA_DW = 16 * ZPAD;
    constexpr int YS_DW = 16 * YSTR;
    constexpr int XS_DW = (EPI == 2) ? 16 * 80 : 0;
    constexpr int SH_DW = (ZA_DW > YS_DW + XS_DW) ? ZA_DW : (YS_DW + XS_DW);
    __shared__ __align__(16) uint32_t sh[SH_DW];    // Za THEN Ys|Xs (union)
    uint32_t* Za = sh;
    float*    Ys = (float*)sh;
    float*    Xs = (float*)(sh + YS_DW);
    int t = threadIdx.x;
    int lane = t & 63;
    int wave = t >> 6;
    int nh = wave & 1, kh = wave >> 1;               // kh in 0..3
    int r0 = blockIdx.x * 16;
    int mrow = lane & 15;
    int q = lane >> 4;

    // ---- stage A tile (16 rows) into LDS, coalesced, no div/mod ----
    {
        int row = t >> 5;                // 16 rows x 32 threads
        int gr = r0 + row; if (gr >= rows) gr = rows - 1;
        const uint4* zr = (const uint4*)Z + (size_t)gr * ZROW;
        for (int off = t & 31; off < ZROW; off += 32)
            *(uint4*)&Za[row * ZPAD + off * 4] = zr[off];
    }
    __syncthreads();

    const bf16x8* mfg = (const bf16x8*)((const uint4*)Mf + lane);
    int base = (NC / 4) * kh + (kh < (NC % 4) ? kh : (NC % 4));
    int cnt  = NC / 4 + (kh < (NC % 4) ? 1 : 0);
    int cka = base, ckz = base + cnt;
    int ntb = nh * 5;
    const uint32_t* zab = &Za[mrow * ZPAD + q * 4];

    f32x4 acc[5];
    #pragma unroll
    for (int nt = 0; nt < 5; nt++) acc[nt] = {0.f, 0.f, 0.f, 0.f};

    // ping-pong buffers (NAMED, both live across MFMAs -> unmergeable)
    bf16x8 pb0[5], pb1[5];
    const bf16x8* pb = mfg + ((size_t)cka * 10 + ntb) * 64;
    #pragma unroll
    for (int nt = 0; nt < 5; nt++) pb0[nt] = pb[nt * 64];

    int ck = cka;
    while (ck < ckz) {
        bool have1 = (ck + 1 < ckz);
        const bf16x8* pn = pb + 640;
        if (have1) {
            #pragma unroll
            for (int nt = 0; nt < 5; nt++) pb1[nt] = pn[nt * 64];
        }
        bf16x8 af0 = *(const bf16x8*)(zab + ck * 16);
        #pragma unroll
        for (int nt = 0; nt < 5; nt++)
            acc[nt] = __builtin_amdgcn_mfma_f32_16x16x32_bf16(af0, pb0[nt],
                                                              acc[nt], 0, 0, 0);
        if (!have1) break;
        bool have2 = (ck + 2 < ckz);
        const bf16x8* pn2 = pn + 640;
        if (have2) {
            #pragma unroll
            for (int nt = 0; nt < 5; nt++) pb0[nt] = pn2[nt * 64];
        }
        bf16x8 af1 = *(const bf16x8*)(zab + (ck + 1) * 16);
        #pragma unroll
        for (int nt = 0; nt < 5; nt++)
            acc[nt] = __builtin_amdgcn_mfma_f32_16x16x32_bf16(af1, pb1[nt],
                                                              acc[nt], 0, 0, 0);
        if (!have2) break;
        pb = pn2;
        ck += 2;
    }

    __syncthreads();    // all waves done reading Za -> union region reusable

    // EPI2: stage x rows into LDS (coalesced); overlaps Ys combine below
    if (EPI == 2) {
        int gbase = blockIdx.x * 16 * 80;
        int glim = rows * 80;
        for (int i = t; i < 16 * 80; i += 512)
            Xs[i] = (gbase + i < glim) ? xres[gbase + i] : 0.f;
    }
    // Ys combine: kh0 writes, then kh1..3 add, barriers between stages.
    // C/D layout: col = lane&15, row = q*4 + reg  [verified m89/m91]
    if (kh == 0) {
        #pragma unroll
        for (int nt = 0; nt < 5; nt++) {
            int col = (ntb + nt) * 16 + mrow;
            #pragma unroll
            for (int reg = 0; reg < 4; reg++)
                Ys[(q * 4 + reg) * YSTR + col] = acc[nt][reg];
        }
    }
    __syncthreads();
    if (kh == 1) {
        #pragma unroll
        for (int nt = 0; nt < 5; nt++) {
            int col = (ntb + nt) * 16 + mrow;
            #pragma unroll
            for (int reg = 0; reg < 4; reg++)
                Ys[(q * 4 + reg) * YSTR + col] += acc[nt][reg];
        }
    }
    __syncthreads();
    if (kh == 2) {
        #pragma unroll
        for (int nt = 0; nt < 5; nt++) {
            int col = (ntb + nt) * 16 + mrow;
            #pragma unroll
            for (int reg = 0; reg < 4; reg++)
                Ys[(q * 4 + reg) * YSTR + col] += acc[nt][reg];
        }
    }
    __syncthreads();
    if (kh == 3) {
        #pragma unroll
        for (int nt = 0; nt < 5; nt++) {
            int col = (ntb + nt) * 16 + mrow;
            #pragma unroll
            for (int reg = 0; reg < 4; reg++)
                Ys[(q * 4 + reg) * YSTR + col] += acc[nt][reg];
        }
    }
    __syncthreads();
    // per-(row,ch) epilogue: 512 threads cover 16 rows x 32 ch exactly
    {
        int row = t >> 5, ch = t & 31;
        int vr = blockIdx.x * 16 + row;
        if (vr < rows) {
            const float* yr = &Ys[row * YSTR + ch * 5];
            float d0 = yr[0], d1 = yr[1], d2 = yr[2], d3 = yr[3], d4 = yr[4];
            float r5[5];
            if (EPI == 1) {
                d0 += bias[ch];
                fourier_relu(d0, d1, d2, d3, d4, r5);
                uint4 o;
                o.x = bf16_rne(r5[0]) | (bf16_rne(r5[1]) << 16);
                o.y = bf16_rne(r5[2]) | (bf16_rne(r5[3]) << 16);
                o.z = bf16_rne(r5[4]);
                o.w = 0;
                y1b[(size_t)vr * 32 + ch] = o;
            } else {
                float rr0 = 0, rr1 = 0, rr2 = 0, rr3 = 0, rr4 = 0;
                const float* xs = &Xs[row * 80];
                const float* wl = Wl + ch * IC1;
                #pragma unroll
                for (int c = 0; c < IC1; c++) {
                    float w = wl[c];
                    rr0 = fmaf(w, xs[c * 5 + 0], rr0);
                    rr1 = fmaf(w, xs[c * 5 + 1], rr1);
                    rr2 = fmaf(w, xs[c * 5 + 2], rr2);
                    rr3 = fmaf(w, xs[c * 5 + 3], rr3);
                    rr4 = fmaf(w, xs[c * 5 + 4], rr4);
                }
                float blo = bl[ch];
                d0 += bias[ch] + rr0 + blo;
                d1 += rr1 + blo;
                d2 += rr2 + blo;
                d3 += rr3 + blo;
                d4 += rr4 + blo;
                fourier_relu(d0, d1, d2, d3, d4, r5);
                float* ob = outp + ((size_t)vr * 32 + ch) * 5;
                #pragma unroll
                for (int d = 0; d < 5; d++) ob[d] = r5[d];
            }
        }
    }
}

extern "C" void kernel_launch(void* const* d_in, const int* in_sizes, int n_in,
                              void* d_out, int out_size, void* d_ws, size_t ws_size,
                              hipStream_t stream) {
    const float* x    = (const float*)d_in[0];
    const int*   ei   = (const int*)  d_in[1];
    const float* pre  = (const float*)d_in[2];
    const float* conn = (const float*)d_in[3];
    const float* W1   = (const float*)d_in[4];
    const float* b1   = (const float*)d_in[5];
    const float* W2   = (const float*)d_in[6];
    const float* b2   = (const float*)d_in[7];
    const float* Wl   = (const float*)d_in[8];
    const float* bl   = (const float*)d_in[9];
    float* out = (float*)d_out;

    const int K1 = IC1 * 50;   // 800
    const int K2 = OC  * 50;   // 1600

    // ws layout (~21MB fixed): M1 | M2 | Mf1 | Mf2 | csr | REC | SRC |
    //   Y1B (10.24MB, ALSO XB1 overlay) | Ztail
    const size_t Y_BYTES   = (size_t)NV * NOUT * sizeof(float);     // 12.8 MB
    const size_t M1_BYTES  = (size_t)K1 * NOUT * sizeof(float);     // 512 KB
    const size_t M2_BYTES  = (size_t)K2 * NOUT * sizeof(float);     // 1 MB
    const size_t MF1_BYTES = (size_t)(K1 / 32) * 10 * 64 * 16;      // 256 KB
    const size_t MF2_BYTES = (size_t)(K2 / 32) * 10 * 64 * 16;      // 512 KB
    const size_t CSR_BYTES = (size_t)(2 * NV) * sizeof(int);        // 160 KB
    const size_t REC_BYTES = (size_t)(NE + 1) * 48;                 // 7.68 MB
    const size_t SRC_BYTES = (((size_t)(NE + 1) * 4 + 15) / 16) * 16;
    const size_t Y1B_BYTES = (size_t)NV * OC * 16;                  // 10.24 MB
    char* ws = (char*)d_ws;
    float* M1 = (float*)(ws);
    float* M2 = (float*)(ws + M1_BYTES);
    uint32_t* Mf1 = (uint32_t*)(ws + M1_BYTES + M2_BYTES);
    uint32_t* Mf2 = (uint32_t*)(ws + M1_BYTES + M2_BYTES + MF1_BYTES);
    int* counts = (int*)(ws + M1_BYTES + M2_BYTES + MF1_BYTES + MF2_BYTES);
    int* cursor = counts + NV;
    size_t csr_end = M1_BYTES + M2_BYTES + MF1_BYTES + MF2_BYTES + CSR_BYTES;
    float4* REC = (float4*)(ws + csr_end);
    int*    SRC = (int*)(ws + csr_end + REC_BYTES);
    uint4*  Y1B = (uint4*)(ws + csr_end + REC_BYTES + SRC_BYTES);
    uint4*  XB1 = Y1B;                            // overlay (disjoint lifetimes)
    size_t fixed = csr_end + REC_BYTES + SRC_BYTES + Y1B_BYTES;

    // Z buffer (bf16): ws tail if it has room, else d_out
    size_t tail = (ws_size > fixed) ? (ws_size - fixed) : 0;
    uint32_t* zbuf;
    size_t zcap;
    if (tail >= Y_BYTES) { zbuf = (uint32_t*)(ws + fixed); zcap = tail; }
    else                 { zbuf = (uint32_t*)d_out;        zcap = Y_BYTES; }
    int chunk1 = (int)(zcap / ((size_t)K1 * 2)); if (chunk1 > NV) chunk1 = NV;
    int chunk2 = (int)(zcap / ((size_t)K2 * 2)); if (chunk2 > NV) chunk2 = NV;
    // balance chunks (e.g. 13125 -> 10000+10000)
    int nch1 = (NV + chunk1 - 1) / chunk1; chunk1 = (NV + nch1 - 1) / nch1;
    int nch2 = (NV + chunk2 - 1) / chunk2; chunk2 = (NV + nch2 - 1) / nch2;

    hipMemsetAsync(counts, 0, NV * sizeof(int), stream);

    build_M<IC1><<<(K1 * NOUT + 255) / 256, 256, 0, stream>>>(W1, M1);
    build_M<OC> <<<(K2 * NOUT + 255) / 256, 256, 0, stream>>>(W2, M2);
    build_Mfrag<K1><<<((K1 / 32) * 2560 + 255) / 256, 256, 0, stream>>>(M1, Mf1);
    build_Mfrag<K2><<<((K2 / 32) * 2560 + 255) / 256, 256, 0, stream>>>(M2, Mf2);

    hist_k<<<(NE + 255) / 256, 256, 0, stream>>>(ei, counts);
    scan_k<<<1, 1024, 0, stream>>>(counts, cursor);
    scatter_pack<<<(NE + 255) / 256, 256, 0, stream>>>(ei, pre, conn, cursor,
                                                       SRC, REC);
    x_pack<<<(NV * IC1 + 255) / 256, 256, 0, stream>>>(x, XB1);

    // layer 1 (fused relu+pack epilogue -> Y1B)
    for (int v0 = 0; v0 < NV; v0 += chunk1) {
        int v1 = v0 + chunk1; if (v1 > NV) v1 = NV;
        int rows = v1 - v0;
        zbuild6<IC1><<<((size_t)rows * IC1 * 2 + 255) / 256, 256, 0, stream>>>(
            XB1, SRC, REC, cursor, zbuf, v0, v1);
        gemm_fused<K1, 1><<<(rows + 15) / 16, 512, 0, stream>>>(
            zbuf, Mf1, rows, Y1B + (size_t)v0 * 32, b1,
            nullptr, nullptr, nullptr, nullptr);
    }
    // layer 2 (fused residual+relu epilogue -> out)
    for (int v0 = 0; v0 < NV; v0 += chunk2) {
        int v1 = v0 + chunk2; if (v1 > NV) v1 = NV;
        int rows = v1 - v0;
        zbuild6<OC><<<((size_t)rows * OC * 2 + 255) / 256, 256, 0, stream>>>(
            Y1B, SRC, REC, cursor, zbuf, v0, v1);
        gemm_fused<K2, 2><<<(rows + 15) / 16, 512, 0, stream>>>(
            zbuf, Mf2, rows, nullptr, b2,
            x + (size_t)v0 * (IC1 * DIN), Wl, bl, out + (size_t)v0 * NOUT);
    }
}